// Round 9
// baseline (377.944 us; speedup 1.0000x reference)
//
#include <hip/hip_runtime.h>
#include <hip/hip_bf16.h>
#include <hip/hip_fp16.h>

// Problem constants
#define BATCH 8
#define SEQ   256
#define CDIM  768
#define DICT  16384
#define TOPK  64
#define NWIN  127          // (256-4)/2 + 1
#define NTOK  (BATCH*SEQ)  // 2048
#define SCAP  192          // screened-candidate cap per window
#define BAND  0.08f        // screening band (~7 sigma of approx wsum error)
#define NBIN  1792         // 4-ulp fp16 histogram bins over [1.0, 128)

typedef short bf16x8 __attribute__((ext_vector_type(8)));
typedef float f32x4  __attribute__((ext_vector_type(4)));
typedef _Float16 f16x8 __attribute__((ext_vector_type(8)));
typedef _Float16 f16x4 __attribute__((ext_vector_type(4)));
typedef _Float16 f16x2 __attribute__((ext_vector_type(2)));
typedef unsigned short u16x8 __attribute__((ext_vector_type(8)));

typedef unsigned int u32_gbl __attribute__((address_space(1)));
typedef unsigned int u32_lds __attribute__((address_space(3)));

__device__ __forceinline__ void gld_lds16(const void* g, void* l) {
    // async 16B/lane global->LDS; LDS dst = wave-uniform base + lane*16
    __builtin_amdgcn_global_load_lds((const u32_gbl*)g, (u32_lds*)l, 16, 0, 0);
}

__device__ __forceinline__ unsigned short f2bf(float f) {   // RNE
    unsigned u = __float_as_uint(f);
    return (unsigned short)((u + 0x7fffu + ((u >> 16) & 1u)) >> 16);
}
__device__ __forceinline__ float bf2f(unsigned short s) {
    return __uint_as_float(((unsigned)s) << 16);
}
__device__ __forceinline__ float h2f_bits(unsigned short b) {
    return (float)__builtin_bit_cast(_Float16, b);
}

// ---------------------------------------------------------------------------
// P0: convert W -> bf16, and x' = (x - b_dec) -> bf16
// ---------------------------------------------------------------------------
__global__ __launch_bounds__(256) void prep(
    const float* __restrict__ W, const float* __restrict__ x,
    const float* __restrict__ bdec,
    unsigned short* __restrict__ Wb, unsigned short* __restrict__ xb)
{
    const long long NW8 = (long long)DICT * CDIM / 8;   // 1,572,864
    const long long NX8 = (long long)NTOK * CDIM / 8;   //   196,608
    long long i = (long long)blockIdx.x * 256 + threadIdx.x;
    if (i < NW8) {
        const float4 f0 = *(const float4*)(W + i * 8);
        const float4 f1 = *(const float4*)(W + i * 8 + 4);
        int4 v;
        v.x = f2bf(f0.x) | (f2bf(f0.y) << 16);
        v.y = f2bf(f0.z) | (f2bf(f0.w) << 16);
        v.z = f2bf(f1.x) | (f2bf(f1.y) << 16);
        v.w = f2bf(f1.z) | (f2bf(f1.w) << 16);
        *(int4*)(Wb + i * 8) = v;
    } else if (i < NW8 + NX8) {
        const long long i2 = i - NW8;
        const int c = (int)((i2 * 8) % CDIM);
        const float4 f0 = *(const float4*)(x + i2 * 8);
        const float4 f1 = *(const float4*)(x + i2 * 8 + 4);
        const float4 d0 = *(const float4*)(bdec + c);
        const float4 d1 = *(const float4*)(bdec + c + 4);
        int4 v;
        v.x = f2bf(f0.x - d0.x) | (f2bf(f0.y - d0.y) << 16);
        v.y = f2bf(f0.z - d0.z) | (f2bf(f0.w - d0.w) << 16);
        v.z = f2bf(f1.x - d1.x) | (f2bf(f1.y - d1.y) << 16);
        v.w = f2bf(f1.z - d1.z) | (f2bf(f1.w - d1.w) << 16);
        *(int4*)(xb + i2 * 8) = v;
    }
}

// ---------------------------------------------------------------------------
// K1: z~ = relu(x' @ Wb^T + b_enc) via bf16 MFMA. v5: 2-phase double-buffered
// K-loop (T3 minimum recipe) — the two 32-k half-buffers alternate; each
// half-step issues the NEXT half's global_load_lds BEFORE its own MFMAs, so
// load latency hides under compute. One barrier per half-step (24 total,
// unchanged count). k-slot swizzle retained (conflicts 6.9M -> 0.6M in r8).
// MFMA accumulation order unchanged (halves ascending) -> bit-identical C.
// ---------------------------------------------------------------------------
__global__ __launch_bounds__(256) void gemm_bf16(
    const unsigned short* __restrict__ xb,   // 2048x768 bf16
    const unsigned short* __restrict__ Wb,   // 16384x768 bf16
    const float* __restrict__ benc,
    unsigned short* __restrict__ wsum,       // (8*127) x 16384 fp16
    unsigned short* __restrict__ zedge,      // 8 x 4 x 16384 fp16
    unsigned short* __restrict__ zh128)      // 2048 x 128 fp16
{
    __shared__ char smem[128 * 136 * 2] __attribute__((aligned(16)));
    unsigned short* As0 = (unsigned short*)smem;         // half-buffer 0 A (8 KB)
    unsigned short* Bs0 = As0 + 128 * 32;                // half-buffer 0 B (8 KB)
    unsigned short* As1 = Bs0 + 128 * 32;                // half-buffer 1 A (8 KB)
    unsigned short* Bs1 = As1 + 128 * 32;                // half-buffer 1 B (8 KB)
    _Float16* CsT = (_Float16*)smem;                     // [128 cols][136 rows] (aliases)

    const int tid = threadIdx.x;
    const int lane = tid & 63, w = tid >> 6;
    const int m0 = blockIdx.x * 128, n0 = blockIdx.y * 128;

    // staging: wave w covers rows 32w..32w+31 in two 16-row issues per buffer.
    // k-slot swizzled: lane stages k-slot ((lane&3) - ((lane>>3)&3)) & 3.
    const int r0 = 32 * w + (lane >> 2);
    const int kb = ((((lane & 3) - ((lane >> 3) & 3)) & 3)) * 8;  // swizzled k
    const unsigned short* gA0 = xb + (size_t)(m0 + r0) * CDIM + kb;
    const unsigned short* gA1 = xb + (size_t)(m0 + r0 + 16) * CDIM + kb;
    const unsigned short* gB0 = Wb + (size_t)(n0 + r0) * CDIM + kb;
    const unsigned short* gB1 = Wb + (size_t)(n0 + r0 + 16) * CDIM + kb;
    unsigned short* lA0 = As0 + (2 * w + 0) * 512;
    unsigned short* lA1 = As0 + (2 * w + 1) * 512;
    unsigned short* lB0 = Bs0 + (2 * w + 0) * 512;
    unsigned short* lB1 = Bs0 + (2 * w + 1) * 512;
    unsigned short* lA0b = As1 + (2 * w + 0) * 512;
    unsigned short* lA1b = As1 + (2 * w + 1) * 512;
    unsigned short* lB0b = Bs1 + (2 * w + 0) * 512;
    unsigned short* lB1b = Bs1 + (2 * w + 1) * 512;

    const int wm = (w & 1) * 64, wn = (w >> 1) * 64;
    const int m16 = lane & 15, qd = lane >> 4;
    const int qds = (qd + ((m16 >> 1) & 3)) & 3;         // swizzled read slot

    f32x4 acc[4][4] = {};

    // prologue: stage half 0 into buffer 0; barrier drains it (vmcnt 0)
    gld_lds16(gA0, lA0);
    gld_lds16(gA1, lA1);
    gld_lds16(gB0, lB0);
    gld_lds16(gB1, lB1);
    __syncthreads();

    // 24 half-steps of 32-k each (CDIM/32), unrolled by 2 for static buffers.
    for (int h = 0; h < 24; h += 2) {
        // even half h: stage half h+1 into buffer 1, compute buffer 0
        {
            const int kn = (h + 1) * 32;         // h+1 <= 23 always
            gld_lds16(gA0 + kn, lA0b);
            gld_lds16(gA1 + kn, lA1b);
            gld_lds16(gB0 + kn, lB0b);
            gld_lds16(gB1 + kn, lB1b);

            bf16x8 af[4], bf[4];
#pragma unroll
            for (int i = 0; i < 4; i++)
                af[i] = *(const bf16x8*)(&As0[(wm + 16 * i + m16) * 32 + qds * 8]);
#pragma unroll
            for (int j = 0; j < 4; j++)
                bf[j] = *(const bf16x8*)(&Bs0[(wn + 16 * j + m16) * 32 + qds * 8]);
#pragma unroll
            for (int i = 0; i < 4; i++)
#pragma unroll
                for (int j = 0; j < 4; j++)
                    acc[i][j] = __builtin_amdgcn_mfma_f32_16x16x32_bf16(
                        af[i], bf[j], acc[i][j], 0, 0, 0);
            __syncthreads();                     // stage(h+1) landed; reads done
        }
        // odd half h+1: stage half h+2 into buffer 0 (if any), compute buffer 1
        {
            if (h + 2 < 24) {
                const int kn = (h + 2) * 32;
                gld_lds16(gA0 + kn, lA0);
                gld_lds16(gA1 + kn, lA1);
                gld_lds16(gB0 + kn, lB0);
                gld_lds16(gB1 + kn, lB1);
            }
            bf16x8 af[4], bf[4];
#pragma unroll
            for (int i = 0; i < 4; i++)
                af[i] = *(const bf16x8*)(&As1[(wm + 16 * i + m16) * 32 + qds * 8]);
#pragma unroll
            for (int j = 0; j < 4; j++)
                bf[j] = *(const bf16x8*)(&Bs1[(wn + 16 * j + m16) * 32 + qds * 8]);
#pragma unroll
            for (int i = 0; i < 4; i++)
#pragma unroll
                for (int j = 0; j < 4; j++)
                    acc[i][j] = __builtin_amdgcn_mfma_f32_16x16x32_bf16(
                        af[i], bf[j], acc[i][j], 0, 0, 0);
            __syncthreads();                     // stage(h+2) landed; reads done
        }
    }
    // all waves synced; LDS free for CsT alias

    // epilogue write: +b_enc, relu -> CsT[col][row], one b64 per acc quad.
    // C/D layout: col=lane&15 (within 16j), row=qd*4+r (within 16i)
#pragma unroll
    for (int j = 0; j < 4; j++) {
        const int col = wn + 16 * j + m16;
        const float bc = benc[n0 + col];
#pragma unroll
        for (int i = 0; i < 4; i++) {
            const int rbase = wm + 16 * i + qd * 4;
            const f32x4 a = acc[i][j];
            f16x4 v;
            v[0] = (_Float16)fmaxf(a[0] + bc, 0.0f);
            v[1] = (_Float16)fmaxf(a[1] + bc, 0.0f);
            v[2] = (_Float16)fmaxf(a[2] + bc, 0.0f);
            v[3] = (_Float16)fmaxf(a[3] + bc, 0.0f);
            *(f16x4*)(&CsT[col * 136 + rbase]) = v;
        }
    }
    __syncthreads();

    const int b = m0 >> 8;                       // batch
    const int tloc = m0 & 255;                   // 0 or 128 within batch
    const int wbase = (tloc == 0) ? 0 : 64;

    // per-column window sums: thread owns col = tid&127, row-half = tid>>7.
    const int col = tid & 127, half = tid >> 7;
    const _Float16* cp = &CsT[col * 136 + half * 64];
    f16x8 r8[8];
#pragma unroll
    for (int k = 0; k < 8; k++) r8[k] = *(const f16x8*)(cp + 8 * k);
    float f[66];
#pragma unroll
    for (int k = 0; k < 8; k++)
#pragma unroll
        for (int e = 0; e < 8; e++) f[8 * k + e] = (float)r8[k][e];
    if (half == 0) {
        const f16x2 t2 = *(const f16x2*)(cp + 64);
        f[64] = (float)t2[0]; f[65] = (float)t2[1];
    } else { f[64] = 0.f; f[65] = 0.f; }

    _Float16* wrow = (_Float16*)wsum;
#pragma unroll
    for (int w2 = 0; w2 < 31; w2++) {
        const float s = (f[2 * w2] + f[2 * w2 + 1]) + (f[2 * w2 + 2] + f[2 * w2 + 3]);
        wrow[(size_t)(b * NWIN + wbase + half * 32 + w2) * DICT + n0 + col] = (_Float16)s;
    }
    if (half == 0) {
        const float s = (f[62] + f[63]) + (f[64] + f[65]);
        wrow[(size_t)(b * NWIN + wbase + 31) * DICT + n0 + col] = (_Float16)s;
    }

    // crossing-window rows
    {
        const int rr = half;
        const int lr0 = (tloc == 0) ? 126 : 0;
        const int slot0 = (tloc == 0) ? 0 : 2;
        const _Float16 v = CsT[col * 136 + lr0 + rr];
        ((_Float16*)zedge)[(size_t)(b * 4 + slot0 + rr) * DICT + n0 + col] = v;
    }

    // z~ cols 0..127 for the zero-fill rule (n-block 0 only)
    if (n0 == 0) {
#pragma unroll
        for (int k = 0; k < 8; k++)
#pragma unroll
            for (int e = 0; e < 8; e++)
                ((_Float16*)zh128)[(size_t)(m0 + half * 64 + 8 * k + e) * 128 + col]
                    = r8[k][e];
    }
}

// ---------------------------------------------------------------------------
// K2+K3 fused: per-window screen + exact fp32 recompute + exact top-64.
// Screen via one-pass 4-ulp LDS histogram (4 barriers), conservative
// threshold, binary-search fallback. Exact phase: TWO candidates per wave
// per iteration (s, s+4; stride 8) — one set of 12 xs LDS reads feeds 96
// FMAs; per-candidate FMA order identical to r7 (bit-identical z values).
// ---------------------------------------------------------------------------
__global__ __launch_bounds__(256) void win_select(
    const unsigned short* __restrict__ wsum, const unsigned short* __restrict__ zedge,
    const float* __restrict__ x, const float* __restrict__ W,
    const float* __restrict__ benc, const float* __restrict__ bdec,
    int* __restrict__ win_idx, float* __restrict__ ztab)
{
    const int wid = blockIdx.x;
    const int b = wid / NWIN, w = wid % NWIN;
    const int t0 = 2 * w;
    const int tid = threadIdx.x;
    const int lane = tid & 63, wvi = tid >> 6;

    __shared__ float xs[4][768];                 // staged x' rows (12 KB)
    __shared__ int hist[NBIN];                   // screen histogram (7 KB)
    __shared__ int cand[SCAP];
    __shared__ float swsum[SCAP];
    __shared__ float sz[SCAP][4];
    __shared__ int sd[SCAP];
    __shared__ int red[2][4];
    __shared__ int s_cnt, s_n1, s_eqc, s_tau, s_B;
    __shared__ int eq_d[SCAP], eq_s[SCAP];
    __shared__ int out_slot[64];

    // stage x' = x - b_dec into LDS (coalesced float4; latency hides under
    // the screen phase). 768 float4s / 256 threads = 3 each.
    {
        const float* xrow = x + (size_t)(b * SEQ + t0) * CDIM;
#pragma unroll
        for (int j = 0; j < 3; j++) {
            const int gi = j * 256 + tid;        // float4 index 0..767
            const int r = gi / 192;              // 192 float4 per row
            const int c4 = (gi - r * 192) * 4;
            const float4 xv = *(const float4*)(xrow + r * CDIM + c4);
            const float4 bd = *(const float4*)(bdec + c4);
            float4 o;
            o.x = xv.x - bd.x; o.y = xv.y - bd.y;
            o.z = xv.z - bd.z; o.w = xv.w - bd.w;
            *(float4*)(&xs[r][c4]) = o;
        }
    }
    if (tid == 0) s_cnt = 0;                     // visible after 1st barrier

    // ---- screen phase ----
    if (w != 63) {
        unsigned short wv[64];
        const unsigned short* row = wsum + (size_t)wid * DICT;
#pragma unroll
        for (int c = 0; c < 8; c++)
            *(u16x8*)(wv + c * 8) = *(const u16x8*)(row + (c * 256 + tid) * 8);

        // build histogram: bin = (bits - 0x3C00) >> 2, clamped
#pragma unroll
        for (int j = 0; j < 7; j++) hist[j * 256 + tid] = 0;
        __syncthreads();
#pragma unroll
        for (int j = 0; j < 64; j++) {
            const unsigned bits = wv[j];
            if (bits >= 0x3C00u) {
                int bin = (int)((bits - 0x3C00u) >> 2);
                bin = min(bin, NBIN - 1);
                atomicAdd(&hist[bin], 1);
            }
        }
        __syncthreads();
        // suffix scan: thread owns bins [7*tid, 7*tid+7), ascending value
        int h[7]; int S = 0;
#pragma unroll
        for (int j = 0; j < 7; j++) { h[j] = hist[7 * tid + j]; S += h[j]; }
        int suf = S;                             // inclusive suffix within wave
#pragma unroll
        for (int off = 1; off < 64; off <<= 1) {
            const int o = __shfl_down(suf, off);
            if (lane + off < 64) suf += o;
        }
        if (lane == 0) red[0][wvi] = suf;        // wave totals
        __syncthreads();
        int hiw = 0;
        for (int u = wvi + 1; u < 4; u++) hiw += red[0][u];
        const int total = red[0][0] + red[0][1] + red[0][2] + red[0][3];
        const int E = hiw + (suf - S);           // excl. suffix (higher tids)
        if (E < 64 && E + S >= 64) {             // unique crossing thread
            int run = E, Bv = -1;
#pragma unroll
            for (int j = 6; j >= 0; j--) {
                run += h[j];
                if (Bv < 0 && run >= 64) Bv = 7 * tid + j;
            }
            s_B = Bv;                            // max bin with suffix >= 64
        }
        __syncthreads();

        if (total >= 64) {
            // tau~ >= h2f(0x3C00 + 4*s_B); thr floored to a representable half
            const float thr =
                h2f_bits((unsigned short)(0x3C00u + ((unsigned)s_B << 2))) - BAND;
            unsigned tb = 0u;
            if (thr > 0.0f) {
                _Float16 th = (_Float16)thr;        // RN
                unsigned short thb = __builtin_bit_cast(unsigned short, th);
                if ((float)th > thr) thb -= 1;
                tb = thb;
            }
#pragma unroll
            for (int c = 0; c < 8; c++) {
#pragma unroll
                for (int e = 0; e < 8; e++) {
                    if ((unsigned)wv[c * 8 + e] > tb) {
                        const int s = atomicAdd(&s_cnt, 1);
                        if (s < SCAP) cand[s] = (c * 256 + tid) * 8 + e;
                    }
                }
            }
            __syncthreads();
        } else {
            // fallback (block-uniform): u16 binary search
            unsigned lo = 0u, hi = 0x5800u;
            int p = 0;
            while (lo < hi) {
                const unsigned mid = (lo + hi) >> 1;
                int c = 0;
#pragma unroll
                for (int j = 0; j < 64; j++) c += ((unsigned)wv[j] > mid) ? 1 : 0;
                for (int off = 32; off > 0; off >>= 1) c += __shfl_down(c, off);
                if (lane == 0) red[p][wvi] = c;
                __syncthreads();
                const int tot = red[p][0] + red[p][1] + red[p][2] + red[p][3];
                if (tot >= 64) lo = mid + 1; else hi = mid;
                p ^= 1;
            }
            const float thr = h2f_bits((unsigned short)lo) - BAND;
            unsigned tb = 0u;
            if (thr > 0.0f) {
                _Float16 th = (_Float16)thr;
                unsigned short thb = __builtin_bit_cast(unsigned short, th);
                if ((float)th > thr) thb -= 1;
                tb = thb;
            }
#pragma unroll
            for (int c = 0; c < 8; c++) {
#pragma unroll
                for (int e = 0; e < 8; e++) {
                    if ((unsigned)wv[c * 8 + e] > tb) {
                        const int s = atomicAdd(&s_cnt, 1);
                        if (s < SCAP) cand[s] = (c * 256 + tid) * 8 + e;
                    }
                }
            }
            __syncthreads();
        }
    } else {
        // crossing window (8 blocks): fp32 sums of 4 halves -> float-domain
        // binary search (identical error budget vs BAND).
        float wf[64];
        const _Float16* e0 = (const _Float16*)zedge + (size_t)b * 4 * DICT;
#pragma unroll
        for (int c = 0; c < 8; c++) {
            const int d8 = (c * 256 + tid) * 8;
            const f16x8 r0 = *(const f16x8*)(e0 + d8);
            const f16x8 r1 = *(const f16x8*)(e0 + DICT + d8);
            const f16x8 r2 = *(const f16x8*)(e0 + 2 * DICT + d8);
            const f16x8 r3 = *(const f16x8*)(e0 + 3 * DICT + d8);
#pragma unroll
            for (int e = 0; e < 8; e++)
                wf[c * 8 + e] = (((float)r0[e] + (float)r1[e]) + (float)r2[e]) + (float)r3[e];
        }
        unsigned lo = 0u, hi = 0x43000000u;        // 128.0f
        int p = 0;
        while (lo < hi) {
            const unsigned mid = (lo + hi) >> 1;
            const float fm = __uint_as_float(mid);
            int c = 0;
#pragma unroll
            for (int j = 0; j < 64; j++) c += (wf[j] > fm) ? 1 : 0;
            for (int off = 32; off > 0; off >>= 1) c += __shfl_down(c, off);
            if (lane == 0) red[p][wvi] = c;
            __syncthreads();
            const int tot = red[p][0] + red[p][1] + red[p][2] + red[p][3];
            if (tot >= 64) lo = mid + 1; else hi = mid;
            p ^= 1;
        }
        const float thr = __uint_as_float(lo) - BAND;
#pragma unroll
        for (int c = 0; c < 8; c++) {
#pragma unroll
            for (int e = 0; e < 8; e++) {
                if (wf[c * 8 + e] > thr) {
                    const int s = atomicAdd(&s_cnt, 1);
                    if (s < SCAP) cand[s] = (c * 256 + tid) * 8 + e;
                }
            }
        }
        __syncthreads();
    }
    const int cnt = min(s_cnt, SCAP);

    // ---- exact phase: fp32 recompute, 2 candidates per wave per iteration.
    // Candidates sA = wvi + 8k, sB = sA + 4. xs reads shared across the pair.
    const int xoff = lane * 4;

    for (int s0 = wvi; s0 < cnt; s0 += 8) {
        const int sA = s0, sB = s0 + 4;
        const bool hasB = (sB < cnt);
        const int dA = cand[sA];
        const int dB = hasB ? cand[sB] : dA;
        const float* wrA = W + (size_t)dA * CDIM + xoff;
        const float* wrB = W + (size_t)dB * CDIM + xoff;
        const float4 wA0 = *(const float4*)(wrA);
        const float4 wA1 = *(const float4*)(wrA + 256);
        const float4 wA2 = *(const float4*)(wrA + 512);
        const float4 wB0 = *(const float4*)(wrB);
        const float4 wB1 = *(const float4*)(wrB + 256);
        const float4 wB2 = *(const float4*)(wrB + 512);
        const float bA = benc[dA];
        const float bB = benc[dB];

        float a0 = 0.f, a1 = 0.f, a2 = 0.f, a3 = 0.f;   // candidate A
        float c0 = 0.f, c1 = 0.f, c2 = 0.f, c3 = 0.f;   // candidate B
        {
            const float4 x00 = *(const float4*)(&xs[0][xoff]);
            const float4 x10 = *(const float4*)(&xs[1][xoff]);
            const float4 x20 = *(const float4*)(&xs[2][xoff]);
            const float4 x30 = *(const float4*)(&xs[3][xoff]);
            a0 = fmaf(x00.x, wA0.x, a0); a0 = fmaf(x00.y, wA0.y, a0);
            a0 = fmaf(x00.z, wA0.z, a0); a0 = fmaf(x00.w, wA0.w, a0);
            a1 = fmaf(x10.x, wA0.x, a1); a1 = fmaf(x10.y, wA0.y, a1);
            a1 = fmaf(x10.z, wA0.z, a1); a1 = fmaf(x10.w, wA0.w, a1);
            a2 = fmaf(x20.x, wA0.x, a2); a2 = fmaf(x20.y, wA0.y, a2);
            a2 = fmaf(x20.z, wA0.z, a2); a2 = fmaf(x20.w, wA0.w, a2);
            a3 = fmaf(x30.x, wA0.x, a3); a3 = fmaf(x30.y, wA0.y, a3);
            a3 = fmaf(x30.z, wA0.z, a3); a3 = fmaf(x30.w, wA0.w, a3);
            c0 = fmaf(x00.x, wB0.x, c0); c0 = fmaf(x00.y, wB0.y, c0);
            c0 = fmaf(x00.z, wB0.z, c0); c0 = fmaf(x00.w, wB0.w, c0);
            c1 = fmaf(x10.x, wB0.x, c1); c1 = fmaf(x10.y, wB0.y, c1);
            c1 = fmaf(x10.z, wB0.z, c1); c1 = fmaf(x10.w, wB0.w, c1);
            c2 = fmaf(x20.x, wB0.x, c2); c2 = fmaf(x20.y, wB0.y, c2);
            c2 = fmaf(x20.z, wB0.z, c2); c2 = fmaf(x20.w, wB0.w, c2);
            c3 = fmaf(x30.x, wB0.x, c3); c3 = fmaf(x30.y, wB0.y, c3);
            c3 = fmaf(x30.z, wB0.z, c3); c3 = fmaf(x30.w, wB0.w, c3);
        }
        {
            const float4 x01 = *(const float4*)(&xs[0][xoff + 256]);
            const float4 x11 = *(const float4*)(&xs[1][xoff + 256]);
            const float4 x21 = *(const float4*)(&xs[2][xoff + 256]);
            const float4 x31 = *(const float4*)(&xs[3][xoff + 256]);
            a0 = fmaf(x01.x, wA1.x, a0); a0 = fmaf(x01.y, wA1.y, a0);
            a0 = fmaf(x01.z, wA1.z, a0); a0 = fmaf(x01.w, wA1.w, a0);
            a1 = fmaf(x11.x, wA1.x, a1); a1 = fmaf(x11.y, wA1.y, a1);
            a1 = fmaf(x11.z, wA1.z, a1); a1 = fmaf(x11.w, wA1.w, a1);
            a2 = fmaf(x21.x, wA1.x, a2); a2 = fmaf(x21.y, wA1.y, a2);
            a2 = fmaf(x21.z, wA1.z, a2); a2 = fmaf(x21.w, wA1.w, a2);
            a3 = fmaf(x31.x, wA1.x, a3); a3 = fmaf(x31.y, wA1.y, a3);
            a3 = fmaf(x31.z, wA1.z, a3); a3 = fmaf(x31.w, wA1.w, a3);
            c0 = fmaf(x01.x, wB1.x, c0); c0 = fmaf(x01.y, wB1.y, c0);
            c0 = fmaf(x01.z, wB1.z, c0); c0 = fmaf(x01.w, wB1.w, c0);
            c1 = fmaf(x11.x, wB1.x, c1); c1 = fmaf(x11.y, wB1.y, c1);
            c1 = fmaf(x11.z, wB1.z, c1); c1 = fmaf(x11.w, wB1.w, c1);
            c2 = fmaf(x21.x, wB1.x, c2); c2 = fmaf(x21.y, wB1.y, c2);
            c2 = fmaf(x21.z, wB1.z, c2); c2 = fmaf(x21.w, wB1.w, c2);
            c3 = fmaf(x31.x, wB1.x, c3); c3 = fmaf(x31.y, wB1.y, c3);
            c3 = fmaf(x31.z, wB1.z, c3); c3 = fmaf(x31.w, wB1.w, c3);
        }
        {
            const float4 x02 = *(const float4*)(&xs[0][xoff + 512]);
            const float4 x12 = *(const float4*)(&xs[1][xoff + 512]);
            const float4 x22 = *(const float4*)(&xs[2][xoff + 512]);
            const float4 x32 = *(const float4*)(&xs[3][xoff + 512]);
            a0 = fmaf(x02.x, wA2.x, a0); a0 = fmaf(x02.y, wA2.y, a0);
            a0 = fmaf(x02.z, wA2.z, a0); a0 = fmaf(x02.w, wA2.w, a0);
            a1 = fmaf(x12.x, wA2.x, a1); a1 = fmaf(x12.y, wA2.y, a1);
            a1 = fmaf(x12.z, wA2.z, a1); a1 = fmaf(x12.w, wA2.w, a1);
            a2 = fmaf(x22.x, wA2.x, a2); a2 = fmaf(x22.y, wA2.y, a2);
            a2 = fmaf(x22.z, wA2.z, a2); a2 = fmaf(x22.w, wA2.w, a2);
            a3 = fmaf(x32.x, wA2.x, a3); a3 = fmaf(x32.y, wA2.y, a3);
            a3 = fmaf(x32.z, wA2.z, a3); a3 = fmaf(x32.w, wA2.w, a3);
            c0 = fmaf(x02.x, wB2.x, c0); c0 = fmaf(x02.y, wB2.y, c0);
            c0 = fmaf(x02.z, wB2.z, c0); c0 = fmaf(x02.w, wB2.w, c0);
            c1 = fmaf(x12.x, wB2.x, c1); c1 = fmaf(x12.y, wB2.y, c1);
            c1 = fmaf(x12.z, wB2.z, c1); c1 = fmaf(x12.w, wB2.w, c1);
            c2 = fmaf(x22.x, wB2.x, c2); c2 = fmaf(x22.y, wB2.y, c2);
            c2 = fmaf(x22.z, wB2.z, c2); c2 = fmaf(x22.w, wB2.w, c2);
            c3 = fmaf(x32.x, wB2.x, c3); c3 = fmaf(x32.y, wB2.y, c3);
            c3 = fmaf(x32.z, wB2.z, c3); c3 = fmaf(x32.w, wB2.w, c3);
        }
        // fold reduction A: 2 exchange levels -> row (lane&3), 4 butterflies
        float xa = (lane & 1) ? a0 : a1;
        xa = __shfl_xor(xa, 1);
        float vA0 = ((lane & 1) ? a1 : a0) + xa;
        float xa2 = (lane & 1) ? a2 : a3;
        xa2 = __shfl_xor(xa2, 1);
        float vA1 = ((lane & 1) ? a3 : a2) + xa2;
        float ya = (lane & 2) ? vA0 : vA1;
        ya = __shfl_xor(ya, 2);
        float vA = ((lane & 2) ? vA1 : vA0) + ya;
        vA += __shfl_xor(vA, 4);
        vA += __shfl_xor(vA, 8);
        vA += __shfl_xor(vA, 16);
        vA += __shfl_xor(vA, 32);                  // lane l: A-total of row (l&3)
        // fold reduction B (independent chain, pipelines with A's)
        float xb2 = (lane & 1) ? c0 : c1;
        xb2 = __shfl_xor(xb2, 1);
        float vB0 = ((lane & 1) ? c1 : c0) + xb2;
        float xb3 = (lane & 1) ? c2 : c3;
        xb3 = __shfl_xor(xb3, 1);
        float vB1 = ((lane & 1) ? c3 : c2) + xb3;
        float yb = (lane & 2) ? vB0 : vB1;
        yb = __shfl_xor(yb, 2);
        float vB = ((lane & 2) ? vB1 : vB0) + yb;
        vB += __shfl_xor(vB, 4);
        vB += __shfl_xor(vB, 8);
        vB += __shfl_xor(vB, 16);
        vB += __shfl_xor(vB, 32);                  // lane l: B-total of row (l&3)

        const float zA = fmaxf(vA + bA, 0.0f);
        if (lane < 4) sz[sA][lane] = zA;
        {
            const float z0 = __shfl(zA, 0), z1 = __shfl(zA, 1);
            const float z2 = __shfl(zA, 2), z3 = __shfl(zA, 3);
            if (lane == 0) {
                sd[sA] = dA;
                swsum[sA] = ((z0 + z1) + z2) + z3;  // original sum order
            }
        }
        if (hasB) {
            const float zB = fmaxf(vB + bB, 0.0f);
            if (lane < 4) sz[sB][lane] = zB;
            const float z0 = __shfl(zB, 0), z1 = __shfl(zB, 1);
            const float z2 = __shfl(zB, 2), z3 = __shfl(zB, 3);
            if (lane == 0) {
                sd[sB] = dB;
                swsum[sB] = ((z0 + z1) + z2) + z3;
            }
        }
    }
    __syncthreads();

    // exact top-64 tau: single wave, 3 values/lane (SCAP=192), barrier-free
    if (wvi == 0) {
        const float v0s = (lane < cnt) ? swsum[lane] : -1.0f;
        const float v1s = (lane + 64 < cnt) ? swsum[lane + 64] : -1.0f;
        const float v2s = (lane + 128 < cnt) ? swsum[lane + 128] : -1.0f;
        unsigned lo = 0u, hi = 0x43000000u;
        while (lo < hi) {
            const unsigned mid = (lo + hi) >> 1;
            const float fm = __uint_as_float(mid);
            int c = ((v0s > fm) ? 1 : 0) + ((v1s > fm) ? 1 : 0) + ((v2s > fm) ? 1 : 0);
#pragma unroll
            for (int off = 32; off > 0; off >>= 1) c += __shfl_down(c, off);
            c = __shfl(c, 0);
            if (c >= 64) lo = mid + 1; else hi = mid;
        }
        if (lane == 0) s_tau = (int)lo;
    }
    __syncthreads();
    const float tau = __uint_as_float((unsigned)s_tau);
    const float vv = (tid < cnt) ? swsum[tid] : -1.0f;

    if (tid == 0) { s_n1 = 0; s_eqc = 0; }
    __syncthreads();
    if (tid < cnt) {
        if (vv > tau) { const int sl = atomicAdd(&s_n1, 1); out_slot[sl] = tid; }
        else if (vv == tau) {
            const int sl = atomicAdd(&s_eqc, 1);
            if (sl < SCAP) { eq_d[sl] = sd[tid]; eq_s[sl] = tid; }
        }
    }
    __syncthreads();
    if (tid == 0) {
        const int n1 = s_n1, need = 64 - n1;
        int ec = min(s_eqc, SCAP);
        for (int a = 0; a < need; a++) {          // lowest-index-first fill
            int best = a;
            for (int q = a + 1; q < ec; q++)
                if (eq_d[q] < eq_d[best]) best = q;
            int td = eq_d[a]; eq_d[a] = eq_d[best]; eq_d[best] = td;
            int ts = eq_s[a]; eq_s[a] = eq_s[best]; eq_s[best] = ts;
            out_slot[n1 + a] = eq_s[a];
        }
    }
    __syncthreads();
    if (tid < 64) {
        const int sl = out_slot[tid];
        win_idx[wid * 64 + tid] = sd[sl];
        float* zt = ztab + (size_t)(wid * 64 + tid) * 4;
        zt[0] = sz[sl][0]; zt[1] = sz[sl][1]; zt[2] = sz[sl][2]; zt[3] = sz[sl][3];
    }
}

// ---------------------------------------------------------------------------
// K5+K6 merged: per-token top-64 (wave 0) + recon from bf16 Wb (reads
// out_i/out_v straight from LDS). No enc writes here -> no race on Wb.
// Also emits the tok lists to d_ws for zero_scatter.
// ---------------------------------------------------------------------------
__global__ __launch_bounds__(256) void tok_recon(
    const int* __restrict__ win_idx, const float* __restrict__ ztab,
    const unsigned short* __restrict__ zh128,
    const unsigned short* __restrict__ Wb, const float* __restrict__ bdec,
    float* __restrict__ recon,
    int* __restrict__ tok_idx, float* __restrict__ tok_val)
{
    const int bid = blockIdx.x;            // token = b*256 + t
    const int t = bid & 255, b = bid >> 8;
    const int tid = threadIdx.x;
    const int lane = tid & 63, wv = tid >> 6;

    __shared__ int l1[64], l2[64];
    __shared__ int out_i[64];
    __shared__ float out_v[64];
    __shared__ int eq_i[130];
    __shared__ float eq_v[130];
    __shared__ int cnt, eqc, s_npos, s_n1;

    const int wlo = (t >= 2) ? ((t - 2) >> 1) : 0;
    int whi = t >> 1; if (whi > NWIN - 1) whi = NWIN - 1;
    const bool valid2 = (whi != wlo);

    int idx1 = -1, idx2 = -1;
    float z1 = 0.f, z2 = 0.f;
    if (wv == 0) {
        const int g1 = (b * NWIN + wlo) * 64 + lane;
        idx1 = win_idx[g1];
        z1 = ztab[(size_t)g1 * 4 + (t - 2 * wlo)];
        if (valid2) {
            const int g2 = (b * NWIN + whi) * 64 + lane;
            idx2 = win_idx[g2];
            z2 = ztab[(size_t)g2 * 4 + (t - 2 * whi)];
        }
        l1[lane] = idx1; l2[lane] = idx2;
        if (lane == 0) { cnt = 0; eqc = 0; s_n1 = 0; }
    }
    __syncthreads();

    if (wv == 0) {
        bool in2 = false, dup2 = false;
        for (int j = 0; j < 64; j++) {
            in2  |= (idx1 == l2[j]);
            dup2 |= (idx2 == l1[j]);
        }
        const float fv1 = in2 ? 2.0f * z1 : z1;
        const bool c2 = valid2 && !dup2;
        const float fv2 = c2 ? z2 : 0.0f;
        const bool pos1 = (fv1 > 0.0f);
        const bool pos2 = c2 && (fv2 > 0.0f);
        const unsigned long long m1 = __ballot(pos1);
        const unsigned long long m2 = __ballot(pos2);
        const int npos = __popcll(m1) + __popcll(m2);
        if (lane == 0) s_npos = npos;

        if (npos > 64) {
            unsigned lo = 0u, hi = 0x43000000u;
            while (lo < hi) {
                const unsigned mid = (lo + hi) >> 1;
                const float fm = __uint_as_float(mid);
                const int c = __popcll(__ballot(pos1 && fv1 > fm)) +
                              __popcll(__ballot(pos2 && fv2 > fm));
                if (c >= 64) lo = mid + 1; else hi = mid;
            }
            const float tau = __uint_as_float(lo);
            const int n1 = __popcll(__ballot(pos1 && fv1 > tau)) +
                           __popcll(__ballot(pos2 && fv2 > tau));
            if (lane == 0) s_n1 = n1;
            if (pos1 && fv1 > tau) { const int s = atomicAdd(&cnt, 1); out_i[s] = idx1; out_v[s] = z1; }
            if (pos2 && fv2 > tau) { const int s = atomicAdd(&cnt, 1); out_i[s] = idx2; out_v[s] = z2; }
            if (pos1 && fv1 == tau) { const int s = atomicAdd(&eqc, 1); if (s < 130) { eq_i[s] = idx1; eq_v[s] = z1; } }
            if (pos2 && fv2 == tau) { const int s = atomicAdd(&eqc, 1); if (s < 130) { eq_i[s] = idx2; eq_v[s] = z2; } }
        } else {
            if (pos1) { const int s = atomicAdd(&cnt, 1); out_i[s] = idx1; out_v[s] = z1; }
            if (pos2) { const int s = atomicAdd(&cnt, 1); out_i[s] = idx2; out_v[s] = z2; }
            const int need = 64 - npos;
            const int d1 = lane, d2 = lane + 64;
            bool ip1 = false, ip2 = false;
            for (int j = 0; j < 64; j++) {
                const int o1 = l1[j]; const bool p1 = (m1 >> j) & 1ull;
                const int o2 = l2[j]; const bool p2 = (m2 >> j) & 1ull;
                ip1 |= (p1 && o1 == d1) || (p2 && o2 == d1);
                ip2 |= (p1 && o1 == d2) || (p2 && o2 == d2);
            }
            const unsigned long long av1 = __ballot(!ip1);
            const unsigned long long av2 = __ballot(!ip2);
            const unsigned long long below = (1ull << lane) - 1ull;
            const int r1 = __popcll(av1 & below);
            const int na1 = __popcll(av1);
            const int r2 = na1 + __popcll(av2 & below);
            if (!ip1 && r1 < need) {
                bool incand = false;
                for (int j = 0; j < 64; j++) incand |= (l1[j] == d1) || (l2[j] == d1);
                const float zv = incand ? 0.0f
                    : (float)((const _Float16*)zh128)[(size_t)bid * 128 + d1];
                const int s = atomicAdd(&cnt, 1); out_i[s] = d1; out_v[s] = zv;
            }
            if (!ip2 && r2 < need) {
                bool incand = false;
                for (int j = 0; j < 64; j++) incand |= (l1[j] == d2) || (l2[j] == d2);
                const float zv = incand ? 0.0f
                    : (float)((const _Float16*)zh128)[(size_t)bid * 128 + d2];
                const int s = atomicAdd(&cnt, 1); out_i[s] = d2; out_v[s] = zv;
            }
        }
    }
    __syncthreads();
    if (tid == 0 && s_npos > 64) {               // tie-fill (lowest index first)
        const int n1 = s_n1, need = 64 - n1;
        int ec = (eqc < 130) ? eqc : 130;
        for (int a = 0; a < need; a++) {
            int best = a;
            for (int q = a + 1; q < ec; q++)
                if (eq_i[q] < eq_i[best]) best = q;
            const int ti = eq_i[a]; eq_i[a] = eq_i[best]; eq_i[best] = ti;
            const float tv = eq_v[a]; eq_v[a] = eq_v[best]; eq_v[best] = tv;
            out_i[n1 + a] = eq_i[a]; out_v[n1 + a] = eq_v[a];
        }
    }
    __syncthreads();

    // tok lists for zero_scatter
    if (tid < 64) {
        tok_idx[bid * 64 + tid] = out_i[tid];
        tok_val[bid * 64 + tid] = out_v[tid];
    }

    // recon from bf16 Wb rows, indices/values from LDS
    if (tid < 192) {
        const int c = tid * 4;                // 4 consecutive cols, 8B in Wb
        const float4 bd = *(const float4*)(bdec + c);
        float a0 = bd.x, a1 = bd.y, a2 = bd.z, a3 = bd.w;
#pragma unroll 8
        for (int j = 0; j < 64; j++) {
            const uint2 pv = *(const uint2*)(Wb + (size_t)out_i[j] * CDIM + c);
            const float vj = out_v[j];
            a0 = fmaf(vj, bf2f((unsigned short)(pv.x & 0xffffu)), a0);
            a1 = fmaf(vj, bf2f((unsigned short)(pv.x >> 16)), a1);
            a2 = fmaf(vj, bf2f((unsigned short)(pv.y & 0xffffu)), a2);
            a3 = fmaf(vj, bf2f((unsigned short)(pv.y >> 16)), a3);
        }
        float4 o; o.x = a0; o.y = a1; o.z = a2; o.w = a3;
        *(float4*)(recon + (size_t)bid * CDIM + c) = o;
    }
}

// ---------------------------------------------------------------------------
// K7: fused zero + scatter (no write amplification)
// ---------------------------------------------------------------------------
__global__ __launch_bounds__(256) void zero_scatter(
    const int* __restrict__ tok_idx, const float* __restrict__ tok_val,
    float* __restrict__ enc)
{
    const int bid = blockIdx.x;
    const int tid = threadIdx.x;
    float* row = enc + (size_t)bid * DICT;
    const float4 z4 = {0.f, 0.f, 0.f, 0.f};
#pragma unroll
    for (int k = 0; k < 16; k++)                 // 256 thr * 16 * 4 = 16384
        *(float4*)(row + (k * 256 + tid) * 4) = z4;
    __syncthreads();
    if (tid < 64)
        row[tok_idx[bid * 64 + tid]] = tok_val[bid * 64 + tid];
}

// ---------------------------------------------------------------------------
extern "C" void kernel_launch(void* const* d_in, const int* in_sizes, int n_in,
                              void* d_out, int out_size, void* d_ws, size_t ws_size,
                              hipStream_t stream)
{
    const float* x    = (const float*)d_in[0];
    const float* Wenc = (const float*)d_in[1];
    const float* benc = (const float*)d_in[2];
    const float* bdec = (const float*)d_in[4];
    (void)in_sizes; (void)n_in; (void)out_size; (void)ws_size;

    float* recon = (float*)d_out;
    float* enc   = recon + (size_t)NTOK * CDIM;          // 134,217,728 bytes

    // scratch layout inside the enc output region (all consumed pre-zero)
    char* base = (char*)enc;
    unsigned short* wsum  = (unsigned short*)(base);                 // 33,292,288
    unsigned short* Wb    = (unsigned short*)(base + 33292288);      // 25,165,824
    unsigned short* xb    = (unsigned short*)(base + 58458112);      //  3,145,728
    unsigned short* zedge = (unsigned short*)(base + 61603840);      //  1,048,576
    unsigned short* zh128 = (unsigned short*)(base + 62652416);      //    524,288
    int*   wini           = (int*)(base + 63176704);                 //    260,096
    float* ztab           = (float*)(base + 63436800);               //  1,040,384

    // tok lists must survive the zeroing -> d_ws (1.0 MB)
    int*   tok_i = (int*)d_ws;
    float* tok_v = (float*)((char*)d_ws + (size_t)NTOK * 64 * 4);

    prep<<<dim3(6912), 256, 0, stream>>>(Wenc, x, bdec, Wb, xb);
    gemm_bf16<<<dim3(NTOK / 128, DICT / 128), 256, 0, stream>>>(xb, Wb, benc,
                                                                wsum, zedge, zh128);
    win_select<<<dim3(BATCH * NWIN), 256, 0, stream>>>(wsum, zedge, x, Wenc,
                                                       benc, bdec, wini, ztab);
    tok_recon<<<dim3(NTOK), 256, 0, stream>>>(wini, ztab, zh128, Wb, bdec,
                                              recon, tok_i, tok_v);
    zero_scatter<<<dim3(NTOK), 256, 0, stream>>>(tok_i, tok_v, enc);
}

// Round 10
// 371.653 us; speedup vs baseline: 1.0169x; 1.0169x over previous
//
#include <hip/hip_runtime.h>
#include <hip/hip_bf16.h>
#include <hip/hip_fp16.h>

// Problem constants
#define BATCH 8
#define SEQ   256
#define CDIM  768
#define DICT  16384
#define TOPK  64
#define NWIN  127          // (256-4)/2 + 1
#define NTOK  (BATCH*SEQ)  // 2048
#define SCAP  192          // screened-candidate cap per window
#define BAND  0.08f        // screening band (~7 sigma of approx wsum error)
#define NBIN  1792         // 4-ulp fp16 histogram bins over [1.0, 128)

typedef short bf16x8 __attribute__((ext_vector_type(8)));
typedef float f32x4  __attribute__((ext_vector_type(4)));
typedef _Float16 f16x8 __attribute__((ext_vector_type(8)));
typedef _Float16 f16x4 __attribute__((ext_vector_type(4)));
typedef _Float16 f16x2 __attribute__((ext_vector_type(2)));
typedef unsigned short u16x8 __attribute__((ext_vector_type(8)));

typedef unsigned int u32_gbl __attribute__((address_space(1)));
typedef unsigned int u32_lds __attribute__((address_space(3)));

__device__ __forceinline__ void gld_lds16(const void* g, void* l) {
    // async 16B/lane global->LDS; LDS dst = wave-uniform base + lane*16
    __builtin_amdgcn_global_load_lds((const u32_gbl*)g, (u32_lds*)l, 16, 0, 0);
}

__device__ __forceinline__ unsigned short f2bf(float f) {   // RNE
    unsigned u = __float_as_uint(f);
    return (unsigned short)((u + 0x7fffu + ((u >> 16) & 1u)) >> 16);
}
__device__ __forceinline__ float bf2f(unsigned short s) {
    return __uint_as_float(((unsigned)s) << 16);
}
__device__ __forceinline__ float h2f_bits(unsigned short b) {
    return (float)__builtin_bit_cast(_Float16, b);
}

// ---------------------------------------------------------------------------
// P0: convert W -> bf16, and x' = (x - b_dec) -> bf16
// ---------------------------------------------------------------------------
__global__ __launch_bounds__(256) void prep(
    const float* __restrict__ W, const float* __restrict__ x,
    const float* __restrict__ bdec,
    unsigned short* __restrict__ Wb, unsigned short* __restrict__ xb)
{
    const long long NW8 = (long long)DICT * CDIM / 8;   // 1,572,864
    const long long NX8 = (long long)NTOK * CDIM / 8;   //   196,608
    long long i = (long long)blockIdx.x * 256 + threadIdx.x;
    if (i < NW8) {
        const float4 f0 = *(const float4*)(W + i * 8);
        const float4 f1 = *(const float4*)(W + i * 8 + 4);
        int4 v;
        v.x = f2bf(f0.x) | (f2bf(f0.y) << 16);
        v.y = f2bf(f0.z) | (f2bf(f0.w) << 16);
        v.z = f2bf(f1.x) | (f2bf(f1.y) << 16);
        v.w = f2bf(f1.z) | (f2bf(f1.w) << 16);
        *(int4*)(Wb + i * 8) = v;
    } else if (i < NW8 + NX8) {
        const long long i2 = i - NW8;
        const int c = (int)((i2 * 8) % CDIM);
        const float4 f0 = *(const float4*)(x + i2 * 8);
        const float4 f1 = *(const float4*)(x + i2 * 8 + 4);
        const float4 d0 = *(const float4*)(bdec + c);
        const float4 d1 = *(const float4*)(bdec + c + 4);
        int4 v;
        v.x = f2bf(f0.x - d0.x) | (f2bf(f0.y - d0.y) << 16);
        v.y = f2bf(f0.z - d0.z) | (f2bf(f0.w - d0.w) << 16);
        v.z = f2bf(f1.x - d1.x) | (f2bf(f1.y - d1.y) << 16);
        v.w = f2bf(f1.z - d1.z) | (f2bf(f1.w - d1.w) << 16);
        *(int4*)(xb + i2 * 8) = v;
    }
}

// ---------------------------------------------------------------------------
// K1: z~ = relu(x' @ Wb^T + b_enc) via bf16 MFMA. v6: 3-buffer counted-vmcnt
// pipeline (T4). Per 32-k phase p: ds_read frags(buf[p%3]) -> lgkmcnt(0)+bar
// (all reads done) -> issue stage(p+3)->buf[p%3] -> 16 MFMA -> vmcnt(8)+bar
// (stage p+1 landed; p+2,p+3 stay IN FLIGHT across the barrier — never drain
// to 0 in the main loop). Tail peeled with vmcnt(4)/vmcnt(0). Safety: buffer
// overwrite gated by the lgkm barrier; consumers gated by per-wave vmcnt +
// barrier; asm "memory" fences pin loads/gld_lds ordering. k-slot swizzle
// retained. MFMA order unchanged (halves ascending) -> bit-identical C.
// ---------------------------------------------------------------------------
__global__ __launch_bounds__(256) void gemm_bf16(
    const unsigned short* __restrict__ xb,   // 2048x768 bf16
    const unsigned short* __restrict__ Wb,   // 16384x768 bf16
    const float* __restrict__ benc,
    unsigned short* __restrict__ wsum,       // (8*127) x 16384 fp16
    unsigned short* __restrict__ zedge,      // 8 x 4 x 16384 fp16
    unsigned short* __restrict__ zh128)      // 2048 x 128 fp16
{
    __shared__ char smem[49152] __attribute__((aligned(16)));  // 3x(A+B) 8KB each
    unsigned short* As0 = (unsigned short*)smem;
    unsigned short* Bs0 = As0 + 128 * 32;
    unsigned short* As1 = Bs0 + 128 * 32;
    unsigned short* Bs1 = As1 + 128 * 32;
    unsigned short* As2 = Bs1 + 128 * 32;
    unsigned short* Bs2 = As2 + 128 * 32;
    _Float16* CsT = (_Float16*)smem;                     // [128][136] aliases (34.8KB)

    const int tid = threadIdx.x;
    const int lane = tid & 63, w = tid >> 6;
    const int m0 = blockIdx.x * 128, n0 = blockIdx.y * 128;

    // staging addressing (k-slot swizzled global source, linear LDS dst)
    const int r0 = 32 * w + (lane >> 2);
    const int kb = ((((lane & 3) - ((lane >> 3) & 3)) & 3)) * 8;
    const unsigned short* gA0 = xb + (size_t)(m0 + r0) * CDIM + kb;
    const unsigned short* gA1 = xb + (size_t)(m0 + r0 + 16) * CDIM + kb;
    const unsigned short* gB0 = Wb + (size_t)(n0 + r0) * CDIM + kb;
    const unsigned short* gB1 = Wb + (size_t)(n0 + r0 + 16) * CDIM + kb;
    const int o0 = (2 * w + 0) * 512, o1 = (2 * w + 1) * 512;

    const int wm = (w & 1) * 64, wn = (w >> 1) * 64;
    const int m16 = lane & 15, qd = lane >> 4;
    const int qds = (qd + ((m16 >> 1) & 3)) & 3;         // swizzled read slot

    f32x4 acc[4][4] = {};

#define STAGE(As_, Bs_, kk) \
    gld_lds16(gA0 + (kk), (As_) + o0); \
    gld_lds16(gA1 + (kk), (As_) + o1); \
    gld_lds16(gB0 + (kk), (Bs_) + o0); \
    gld_lds16(gB1 + (kk), (Bs_) + o1);

#define LOADFRAG(As_, Bs_) \
    _Pragma("unroll") \
    for (int i = 0; i < 4; i++) \
        af[i] = *(const bf16x8*)(&(As_)[(wm + 16 * i + m16) * 32 + qds * 8]); \
    _Pragma("unroll") \
    for (int j = 0; j < 4; j++) \
        bf[j] = *(const bf16x8*)(&(Bs_)[(wn + 16 * j + m16) * 32 + qds * 8]);

#define DO_MFMA() \
    _Pragma("unroll") \
    for (int i = 0; i < 4; i++) \
        _Pragma("unroll") \
        for (int j = 0; j < 4; j++) \
            acc[i][j] = __builtin_amdgcn_mfma_f32_16x16x32_bf16( \
                af[i], bf[j], acc[i][j], 0, 0, 0);

    // prologue: stages 0,1,2 in flight; wait stage 0 only (8 remain)
    STAGE(As0, Bs0, 0);
    STAGE(As1, Bs1, 32);
    STAGE(As2, Bs2, 64);
    asm volatile("s_waitcnt vmcnt(8)" ::: "memory");
    __builtin_amdgcn_s_barrier();

    // main phases 0..20 (each stages p+3; 3..23 all covered)
    for (int h = 0; h < 21; h += 3) {
        {   // phase h: buf0
            bf16x8 af[4], bf[4];
            LOADFRAG(As0, Bs0);
            asm volatile("s_waitcnt lgkmcnt(0)" ::: "memory");
            __builtin_amdgcn_s_barrier();          // all reads of buf0 done
            STAGE(As0, Bs0, (h + 3) * 32);
            DO_MFMA();
            asm volatile("s_waitcnt vmcnt(8)" ::: "memory");
            __builtin_amdgcn_s_barrier();          // stage(h+1) landed
        }
        {   // phase h+1: buf1
            bf16x8 af[4], bf[4];
            LOADFRAG(As1, Bs1);
            asm volatile("s_waitcnt lgkmcnt(0)" ::: "memory");
            __builtin_amdgcn_s_barrier();
            STAGE(As1, Bs1, (h + 4) * 32);
            DO_MFMA();
            asm volatile("s_waitcnt vmcnt(8)" ::: "memory");
            __builtin_amdgcn_s_barrier();
        }
        {   // phase h+2: buf2
            bf16x8 af[4], bf[4];
            LOADFRAG(As2, Bs2);
            asm volatile("s_waitcnt lgkmcnt(0)" ::: "memory");
            __builtin_amdgcn_s_barrier();
            STAGE(As2, Bs2, (h + 5) * 32);
            DO_MFMA();
            asm volatile("s_waitcnt vmcnt(8)" ::: "memory");
            __builtin_amdgcn_s_barrier();
        }
    }
    {   // phase 21: buf0 (stage 21 landed; 22,23 in flight). No stage-issue.
        bf16x8 af[4], bf[4];
        LOADFRAG(As0, Bs0);
        DO_MFMA();
        asm volatile("s_waitcnt vmcnt(4)" ::: "memory");   // stage 22 landed
        __builtin_amdgcn_s_barrier();
    }
    {   // phase 22: buf1
        bf16x8 af[4], bf[4];
        LOADFRAG(As1, Bs1);
        DO_MFMA();
        asm volatile("s_waitcnt vmcnt(0)" ::: "memory");   // stage 23 landed
        __builtin_amdgcn_s_barrier();
    }
    {   // phase 23: buf2
        bf16x8 af[4], bf[4];
        LOADFRAG(As2, Bs2);
        DO_MFMA();
    }
    __syncthreads();                             // full drain; LDS free for CsT

#undef STAGE
#undef LOADFRAG
#undef DO_MFMA

    // epilogue write: +b_enc, relu -> CsT[col][row], one b64 per acc quad.
    // C/D layout: col=lane&15 (within 16j), row=qd*4+r (within 16i)
#pragma unroll
    for (int j = 0; j < 4; j++) {
        const int col = wn + 16 * j + m16;
        const float bc = benc[n0 + col];
#pragma unroll
        for (int i = 0; i < 4; i++) {
            const int rbase = wm + 16 * i + qd * 4;
            const f32x4 a = acc[i][j];
            f16x4 v;
            v[0] = (_Float16)fmaxf(a[0] + bc, 0.0f);
            v[1] = (_Float16)fmaxf(a[1] + bc, 0.0f);
            v[2] = (_Float16)fmaxf(a[2] + bc, 0.0f);
            v[3] = (_Float16)fmaxf(a[3] + bc, 0.0f);
            *(f16x4*)(&CsT[col * 136 + rbase]) = v;
        }
    }
    __syncthreads();

    const int b = m0 >> 8;                       // batch
    const int tloc = m0 & 255;                   // 0 or 128 within batch
    const int wbase = (tloc == 0) ? 0 : 64;

    // per-column window sums: thread owns col = tid&127, row-half = tid>>7.
    const int col = tid & 127, half = tid >> 7;
    const _Float16* cp = &CsT[col * 136 + half * 64];
    f16x8 r8[8];
#pragma unroll
    for (int k = 0; k < 8; k++) r8[k] = *(const f16x8*)(cp + 8 * k);
    float f[66];
#pragma unroll
    for (int k = 0; k < 8; k++)
#pragma unroll
        for (int e = 0; e < 8; e++) f[8 * k + e] = (float)r8[k][e];
    if (half == 0) {
        const f16x2 t2 = *(const f16x2*)(cp + 64);
        f[64] = (float)t2[0]; f[65] = (float)t2[1];
    } else { f[64] = 0.f; f[65] = 0.f; }

    _Float16* wrow = (_Float16*)wsum;
#pragma unroll
    for (int w2 = 0; w2 < 31; w2++) {
        const float s = (f[2 * w2] + f[2 * w2 + 1]) + (f[2 * w2 + 2] + f[2 * w2 + 3]);
        wrow[(size_t)(b * NWIN + wbase + half * 32 + w2) * DICT + n0 + col] = (_Float16)s;
    }
    if (half == 0) {
        const float s = (f[62] + f[63]) + (f[64] + f[65]);
        wrow[(size_t)(b * NWIN + wbase + 31) * DICT + n0 + col] = (_Float16)s;
    }

    // crossing-window rows
    {
        const int rr = half;
        const int lr0 = (tloc == 0) ? 126 : 0;
        const int slot0 = (tloc == 0) ? 0 : 2;
        const _Float16 v = CsT[col * 136 + lr0 + rr];
        ((_Float16*)zedge)[(size_t)(b * 4 + slot0 + rr) * DICT + n0 + col] = v;
    }

    // z~ cols 0..127 for the zero-fill rule (n-block 0 only)
    if (n0 == 0) {
#pragma unroll
        for (int k = 0; k < 8; k++)
#pragma unroll
            for (int e = 0; e < 8; e++)
                ((_Float16*)zh128)[(size_t)(m0 + half * 64 + 8 * k + e) * 128 + col]
                    = r8[k][e];
    }
}

// ---------------------------------------------------------------------------
// K2+K3 fused: per-window screen + exact fp32 recompute + exact top-64.
// Screen via one-pass 4-ulp LDS histogram (4 barriers), conservative
// threshold, binary-search fallback. Exact phase: TWO candidates per wave
// per iteration (s, s+4; stride 8) — one set of 12 xs LDS reads feeds 96
// FMAs; per-candidate FMA order identical to r7 (bit-identical z values).
// ---------------------------------------------------------------------------
__global__ __launch_bounds__(256) void win_select(
    const unsigned short* __restrict__ wsum, const unsigned short* __restrict__ zedge,
    const float* __restrict__ x, const float* __restrict__ W,
    const float* __restrict__ benc, const float* __restrict__ bdec,
    int* __restrict__ win_idx, float* __restrict__ ztab)
{
    const int wid = blockIdx.x;
    const int b = wid / NWIN, w = wid % NWIN;
    const int t0 = 2 * w;
    const int tid = threadIdx.x;
    const int lane = tid & 63, wvi = tid >> 6;

    __shared__ float xs[4][768];                 // staged x' rows (12 KB)
    __shared__ int hist[NBIN];                   // screen histogram (7 KB)
    __shared__ int cand[SCAP];
    __shared__ float swsum[SCAP];
    __shared__ float sz[SCAP][4];
    __shared__ int sd[SCAP];
    __shared__ int red[2][4];
    __shared__ int s_cnt, s_n1, s_eqc, s_tau, s_B;
    __shared__ int eq_d[SCAP], eq_s[SCAP];
    __shared__ int out_slot[64];

    // stage x' = x - b_dec into LDS (coalesced float4; latency hides under
    // the screen phase). 768 float4s / 256 threads = 3 each.
    {
        const float* xrow = x + (size_t)(b * SEQ + t0) * CDIM;
#pragma unroll
        for (int j = 0; j < 3; j++) {
            const int gi = j * 256 + tid;        // float4 index 0..767
            const int r = gi / 192;              // 192 float4 per row
            const int c4 = (gi - r * 192) * 4;
            const float4 xv = *(const float4*)(xrow + r * CDIM + c4);
            const float4 bd = *(const float4*)(bdec + c4);
            float4 o;
            o.x = xv.x - bd.x; o.y = xv.y - bd.y;
            o.z = xv.z - bd.z; o.w = xv.w - bd.w;
            *(float4*)(&xs[r][c4]) = o;
        }
    }
    if (tid == 0) s_cnt = 0;                     // visible after 1st barrier

    // ---- screen phase ----
    if (w != 63) {
        unsigned short wv[64];
        const unsigned short* row = wsum + (size_t)wid * DICT;
#pragma unroll
        for (int c = 0; c < 8; c++)
            *(u16x8*)(wv + c * 8) = *(const u16x8*)(row + (c * 256 + tid) * 8);

        // build histogram: bin = (bits - 0x3C00) >> 2, clamped
#pragma unroll
        for (int j = 0; j < 7; j++) hist[j * 256 + tid] = 0;
        __syncthreads();
#pragma unroll
        for (int j = 0; j < 64; j++) {
            const unsigned bits = wv[j];
            if (bits >= 0x3C00u) {
                int bin = (int)((bits - 0x3C00u) >> 2);
                bin = min(bin, NBIN - 1);
                atomicAdd(&hist[bin], 1);
            }
        }
        __syncthreads();
        // suffix scan: thread owns bins [7*tid, 7*tid+7), ascending value
        int h[7]; int S = 0;
#pragma unroll
        for (int j = 0; j < 7; j++) { h[j] = hist[7 * tid + j]; S += h[j]; }
        int suf = S;                             // inclusive suffix within wave
#pragma unroll
        for (int off = 1; off < 64; off <<= 1) {
            const int o = __shfl_down(suf, off);
            if (lane + off < 64) suf += o;
        }
        if (lane == 0) red[0][wvi] = suf;        // wave totals
        __syncthreads();
        int hiw = 0;
        for (int u = wvi + 1; u < 4; u++) hiw += red[0][u];
        const int total = red[0][0] + red[0][1] + red[0][2] + red[0][3];
        const int E = hiw + (suf - S);           // excl. suffix (higher tids)
        if (E < 64 && E + S >= 64) {             // unique crossing thread
            int run = E, Bv = -1;
#pragma unroll
            for (int j = 6; j >= 0; j--) {
                run += h[j];
                if (Bv < 0 && run >= 64) Bv = 7 * tid + j;
            }
            s_B = Bv;                            // max bin with suffix >= 64
        }
        __syncthreads();

        if (total >= 64) {
            // tau~ >= h2f(0x3C00 + 4*s_B); thr floored to a representable half
            const float thr =
                h2f_bits((unsigned short)(0x3C00u + ((unsigned)s_B << 2))) - BAND;
            unsigned tb = 0u;
            if (thr > 0.0f) {
                _Float16 th = (_Float16)thr;        // RN
                unsigned short thb = __builtin_bit_cast(unsigned short, th);
                if ((float)th > thr) thb -= 1;
                tb = thb;
            }
#pragma unroll
            for (int c = 0; c < 8; c++) {
#pragma unroll
                for (int e = 0; e < 8; e++) {
                    if ((unsigned)wv[c * 8 + e] > tb) {
                        const int s = atomicAdd(&s_cnt, 1);
                        if (s < SCAP) cand[s] = (c * 256 + tid) * 8 + e;
                    }
                }
            }
            __syncthreads();
        } else {
            // fallback (block-uniform): u16 binary search
            unsigned lo = 0u, hi = 0x5800u;
            int p = 0;
            while (lo < hi) {
                const unsigned mid = (lo + hi) >> 1;
                int c = 0;
#pragma unroll
                for (int j = 0; j < 64; j++) c += ((unsigned)wv[j] > mid) ? 1 : 0;
                for (int off = 32; off > 0; off >>= 1) c += __shfl_down(c, off);
                if (lane == 0) red[p][wvi] = c;
                __syncthreads();
                const int tot = red[p][0] + red[p][1] + red[p][2] + red[p][3];
                if (tot >= 64) lo = mid + 1; else hi = mid;
                p ^= 1;
            }
            const float thr = h2f_bits((unsigned short)lo) - BAND;
            unsigned tb = 0u;
            if (thr > 0.0f) {
                _Float16 th = (_Float16)thr;
                unsigned short thb = __builtin_bit_cast(unsigned short, th);
                if ((float)th > thr) thb -= 1;
                tb = thb;
            }
#pragma unroll
            for (int c = 0; c < 8; c++) {
#pragma unroll
                for (int e = 0; e < 8; e++) {
                    if ((unsigned)wv[c * 8 + e] > tb) {
                        const int s = atomicAdd(&s_cnt, 1);
                        if (s < SCAP) cand[s] = (c * 256 + tid) * 8 + e;
                    }
                }
            }
            __syncthreads();
        }
    } else {
        // crossing window (8 blocks): fp32 sums of 4 halves -> float-domain
        // binary search (identical error budget vs BAND).
        float wf[64];
        const _Float16* e0 = (const _Float16*)zedge + (size_t)b * 4 * DICT;
#pragma unroll
        for (int c = 0; c < 8; c++) {
            const int d8 = (c * 256 + tid) * 8;
            const f16x8 r0 = *(const f16x8*)(e0 + d8);
            const f16x8 r1 = *(const f16x8*)(e0 + DICT + d8);
            const f16x8 r2 = *(const f16x8*)(e0 + 2 * DICT + d8);
            const f16x8 r3 = *(const f16x8*)(e0 + 3 * DICT + d8);
#pragma unroll
            for (int e = 0; e < 8; e++)
                wf[c * 8 + e] = (((float)r0[e] + (float)r1[e]) + (float)r2[e]) + (float)r3[e];
        }
        unsigned lo = 0u, hi = 0x43000000u;        // 128.0f
        int p = 0;
        while (lo < hi) {
            const unsigned mid = (lo + hi) >> 1;
            const float fm = __uint_as_float(mid);
            int c = 0;
#pragma unroll
            for (int j = 0; j < 64; j++) c += (wf[j] > fm) ? 1 : 0;
            for (int off = 32; off > 0; off >>= 1) c += __shfl_down(c, off);
            if (lane == 0) red[p][wvi] = c;
            __syncthreads();
            const int tot = red[p][0] + red[p][1] + red[p][2] + red[p][3];
            if (tot >= 64) lo = mid + 1; else hi = mid;
            p ^= 1;
        }
        const float thr = __uint_as_float(lo) - BAND;
#pragma unroll
        for (int c = 0; c < 8; c++) {
#pragma unroll
            for (int e = 0; e < 8; e++) {
                if (wf[c * 8 + e] > thr) {
                    const int s = atomicAdd(&s_cnt, 1);
                    if (s < SCAP) cand[s] = (c * 256 + tid) * 8 + e;
                }
            }
        }
        __syncthreads();
    }
    const int cnt = min(s_cnt, SCAP);

    // ---- exact phase: fp32 recompute, 2 candidates per wave per iteration.
    // Candidates sA = wvi + 8k, sB = sA + 4. xs reads shared across the pair.
    const int xoff = lane * 4;

    for (int s0 = wvi; s0 < cnt; s0 += 8) {
        const int sA = s0, sB = s0 + 4;
        const bool hasB = (sB < cnt);
        const int dA = cand[sA];
        const int dB = hasB ? cand[sB] : dA;
        const float* wrA = W + (size_t)dA * CDIM + xoff;
        const float* wrB = W + (size_t)dB * CDIM + xoff;
        const float4 wA0 = *(const float4*)(wrA);
        const float4 wA1 = *(const float4*)(wrA + 256);
        const float4 wA2 = *(const float4*)(wrA + 512);
        const float4 wB0 = *(const float4*)(wrB);
        const float4 wB1 = *(const float4*)(wrB + 256);
        const float4 wB2 = *(const float4*)(wrB + 512);
        const float bA = benc[dA];
        const float bB = benc[dB];

        float a0 = 0.f, a1 = 0.f, a2 = 0.f, a3 = 0.f;   // candidate A
        float c0 = 0.f, c1 = 0.f, c2 = 0.f, c3 = 0.f;   // candidate B
        {
            const float4 x00 = *(const float4*)(&xs[0][xoff]);
            const float4 x10 = *(const float4*)(&xs[1][xoff]);
            const float4 x20 = *(const float4*)(&xs[2][xoff]);
            const float4 x30 = *(const float4*)(&xs[3][xoff]);
            a0 = fmaf(x00.x, wA0.x, a0); a0 = fmaf(x00.y, wA0.y, a0);
            a0 = fmaf(x00.z, wA0.z, a0); a0 = fmaf(x00.w, wA0.w, a0);
            a1 = fmaf(x10.x, wA0.x, a1); a1 = fmaf(x10.y, wA0.y, a1);
            a1 = fmaf(x10.z, wA0.z, a1); a1 = fmaf(x10.w, wA0.w, a1);
            a2 = fmaf(x20.x, wA0.x, a2); a2 = fmaf(x20.y, wA0.y, a2);
            a2 = fmaf(x20.z, wA0.z, a2); a2 = fmaf(x20.w, wA0.w, a2);
            a3 = fmaf(x30.x, wA0.x, a3); a3 = fmaf(x30.y, wA0.y, a3);
            a3 = fmaf(x30.z, wA0.z, a3); a3 = fmaf(x30.w, wA0.w, a3);
            c0 = fmaf(x00.x, wB0.x, c0); c0 = fmaf(x00.y, wB0.y, c0);
            c0 = fmaf(x00.z, wB0.z, c0); c0 = fmaf(x00.w, wB0.w, c0);
            c1 = fmaf(x10.x, wB0.x, c1); c1 = fmaf(x10.y, wB0.y, c1);
            c1 = fmaf(x10.z, wB0.z, c1); c1 = fmaf(x10.w, wB0.w, c1);
            c2 = fmaf(x20.x, wB0.x, c2); c2 = fmaf(x20.y, wB0.y, c2);
            c2 = fmaf(x20.z, wB0.z, c2); c2 = fmaf(x20.w, wB0.w, c2);
            c3 = fmaf(x30.x, wB0.x, c3); c3 = fmaf(x30.y, wB0.y, c3);
            c3 = fmaf(x30.z, wB0.z, c3); c3 = fmaf(x30.w, wB0.w, c3);
        }
        {
            const float4 x01 = *(const float4*)(&xs[0][xoff + 256]);
            const float4 x11 = *(const float4*)(&xs[1][xoff + 256]);
            const float4 x21 = *(const float4*)(&xs[2][xoff + 256]);
            const float4 x31 = *(const float4*)(&xs[3][xoff + 256]);
            a0 = fmaf(x01.x, wA1.x, a0); a0 = fmaf(x01.y, wA1.y, a0);
            a0 = fmaf(x01.z, wA1.z, a0); a0 = fmaf(x01.w, wA1.w, a0);
            a1 = fmaf(x11.x, wA1.x, a1); a1 = fmaf(x11.y, wA1.y, a1);
            a1 = fmaf(x11.z, wA1.z, a1); a1 = fmaf(x11.w, wA1.w, a1);
            a2 = fmaf(x21.x, wA1.x, a2); a2 = fmaf(x21.y, wA1.y, a2);
            a2 = fmaf(x21.z, wA1.z, a2); a2 = fmaf(x21.w, wA1.w, a2);
            a3 = fmaf(x31.x, wA1.x, a3); a3 = fmaf(x31.y, wA1.y, a3);
            a3 = fmaf(x31.z, wA1.z, a3); a3 = fmaf(x31.w, wA1.w, a3);
            c0 = fmaf(x01.x, wB1.x, c0); c0 = fmaf(x01.y, wB1.y, c0);
            c0 = fmaf(x01.z, wB1.z, c0); c0 = fmaf(x01.w, wB1.w, c0);
            c1 = fmaf(x11.x, wB1.x, c1); c1 = fmaf(x11.y, wB1.y, c1);
            c1 = fmaf(x11.z, wB1.z, c1); c1 = fmaf(x11.w, wB1.w, c1);
            c2 = fmaf(x21.x, wB1.x, c2); c2 = fmaf(x21.y, wB1.y, c2);
            c2 = fmaf(x21.z, wB1.z, c2); c2 = fmaf(x21.w, wB1.w, c2);
            c3 = fmaf(x31.x, wB1.x, c3); c3 = fmaf(x31.y, wB1.y, c3);
            c3 = fmaf(x31.z, wB1.z, c3); c3 = fmaf(x31.w, wB1.w, c3);
        }
        {
            const float4 x02 = *(const float4*)(&xs[0][xoff + 512]);
            const float4 x12 = *(const float4*)(&xs[1][xoff + 512]);
            const float4 x22 = *(const float4*)(&xs[2][xoff + 512]);
            const float4 x32 = *(const float4*)(&xs[3][xoff + 512]);
            a0 = fmaf(x02.x, wA2.x, a0); a0 = fmaf(x02.y, wA2.y, a0);
            a0 = fmaf(x02.z, wA2.z, a0); a0 = fmaf(x02.w, wA2.w, a0);
            a1 = fmaf(x12.x, wA2.x, a1); a1 = fmaf(x12.y, wA2.y, a1);
            a1 = fmaf(x12.z, wA2.z, a1); a1 = fmaf(x12.w, wA2.w, a1);
            a2 = fmaf(x22.x, wA2.x, a2); a2 = fmaf(x22.y, wA2.y, a2);
            a2 = fmaf(x22.z, wA2.z, a2); a2 = fmaf(x22.w, wA2.w, a2);
            a3 = fmaf(x32.x, wA2.x, a3); a3 = fmaf(x32.y, wA2.y, a3);
            a3 = fmaf(x32.z, wA2.z, a3); a3 = fmaf(x32.w, wA2.w, a3);
            c0 = fmaf(x02.x, wB2.x, c0); c0 = fmaf(x02.y, wB2.y, c0);
            c0 = fmaf(x02.z, wB2.z, c0); c0 = fmaf(x02.w, wB2.w, c0);
            c1 = fmaf(x12.x, wB2.x, c1); c1 = fmaf(x12.y, wB2.y, c1);
            c1 = fmaf(x12.z, wB2.z, c1); c1 = fmaf(x12.w, wB2.w, c1);
            c2 = fmaf(x22.x, wB2.x, c2); c2 = fmaf(x22.y, wB2.y, c2);
            c2 = fmaf(x22.z, wB2.z, c2); c2 = fmaf(x22.w, wB2.w, c2);
            c3 = fmaf(x32.x, wB2.x, c3); c3 = fmaf(x32.y, wB2.y, c3);
            c3 = fmaf(x32.z, wB2.z, c3); c3 = fmaf(x32.w, wB2.w, c3);
        }
        // fold reduction A: 2 exchange levels -> row (lane&3), 4 butterflies
        float xa = (lane & 1) ? a0 : a1;
        xa = __shfl_xor(xa, 1);
        float vA0 = ((lane & 1) ? a1 : a0) + xa;
        float xa2 = (lane & 1) ? a2 : a3;
        xa2 = __shfl_xor(xa2, 1);
        float vA1 = ((lane & 1) ? a3 : a2) + xa2;
        float ya = (lane & 2) ? vA0 : vA1;
        ya = __shfl_xor(ya, 2);
        float vA = ((lane & 2) ? vA1 : vA0) + ya;
        vA += __shfl_xor(vA, 4);
        vA += __shfl_xor(vA, 8);
        vA += __shfl_xor(vA, 16);
        vA += __shfl_xor(vA, 32);                  // lane l: A-total of row (l&3)
        // fold reduction B (independent chain, pipelines with A's)
        float xb2 = (lane & 1) ? c0 : c1;
        xb2 = __shfl_xor(xb2, 1);
        float vB0 = ((lane & 1) ? c1 : c0) + xb2;
        float xb3 = (lane & 1) ? c2 : c3;
        xb3 = __shfl_xor(xb3, 1);
        float vB1 = ((lane & 1) ? c3 : c2) + xb3;
        float yb = (lane & 2) ? vB0 : vB1;
        yb = __shfl_xor(yb, 2);
        float vB = ((lane & 2) ? vB1 : vB0) + yb;
        vB += __shfl_xor(vB, 4);
        vB += __shfl_xor(vB, 8);
        vB += __shfl_xor(vB, 16);
        vB += __shfl_xor(vB, 32);                  // lane l: B-total of row (l&3)

        const float zA = fmaxf(vA + bA, 0.0f);
        if (lane < 4) sz[sA][lane] = zA;
        {
            const float z0 = __shfl(zA, 0), z1 = __shfl(zA, 1);
            const float z2 = __shfl(zA, 2), z3 = __shfl(zA, 3);
            if (lane == 0) {
                sd[sA] = dA;
                swsum[sA] = ((z0 + z1) + z2) + z3;  // original sum order
            }
        }
        if (hasB) {
            const float zB = fmaxf(vB + bB, 0.0f);
            if (lane < 4) sz[sB][lane] = zB;
            const float z0 = __shfl(zB, 0), z1 = __shfl(zB, 1);
            const float z2 = __shfl(zB, 2), z3 = __shfl(zB, 3);
            if (lane == 0) {
                sd[sB] = dB;
                swsum[sB] = ((z0 + z1) + z2) + z3;
            }
        }
    }
    __syncthreads();

    // exact top-64 tau: single wave, 3 values/lane (SCAP=192), barrier-free
    if (wvi == 0) {
        const float v0s = (lane < cnt) ? swsum[lane] : -1.0f;
        const float v1s = (lane + 64 < cnt) ? swsum[lane + 64] : -1.0f;
        const float v2s = (lane + 128 < cnt) ? swsum[lane + 128] : -1.0f;
        unsigned lo = 0u, hi = 0x43000000u;
        while (lo < hi) {
            const unsigned mid = (lo + hi) >> 1;
            const float fm = __uint_as_float(mid);
            int c = ((v0s > fm) ? 1 : 0) + ((v1s > fm) ? 1 : 0) + ((v2s > fm) ? 1 : 0);
#pragma unroll
            for (int off = 32; off > 0; off >>= 1) c += __shfl_down(c, off);
            c = __shfl(c, 0);
            if (c >= 64) lo = mid + 1; else hi = mid;
        }
        if (lane == 0) s_tau = (int)lo;
    }
    __syncthreads();
    const float tau = __uint_as_float((unsigned)s_tau);
    const float vv = (tid < cnt) ? swsum[tid] : -1.0f;

    if (tid == 0) { s_n1 = 0; s_eqc = 0; }
    __syncthreads();
    if (tid < cnt) {
        if (vv > tau) { const int sl = atomicAdd(&s_n1, 1); out_slot[sl] = tid; }
        else if (vv == tau) {
            const int sl = atomicAdd(&s_eqc, 1);
            if (sl < SCAP) { eq_d[sl] = sd[tid]; eq_s[sl] = tid; }
        }
    }
    __syncthreads();
    if (tid == 0) {
        const int n1 = s_n1, need = 64 - n1;
        int ec = min(s_eqc, SCAP);
        for (int a = 0; a < need; a++) {          // lowest-index-first fill
            int best = a;
            for (int q = a + 1; q < ec; q++)
                if (eq_d[q] < eq_d[best]) best = q;
            int td = eq_d[a]; eq_d[a] = eq_d[best]; eq_d[best] = td;
            int ts = eq_s[a]; eq_s[a] = eq_s[best]; eq_s[best] = ts;
            out_slot[n1 + a] = eq_s[a];
        }
    }
    __syncthreads();
    if (tid < 64) {
        const int sl = out_slot[tid];
        win_idx[wid * 64 + tid] = sd[sl];
        float* zt = ztab + (size_t)(wid * 64 + tid) * 4;
        zt[0] = sz[sl][0]; zt[1] = sz[sl][1]; zt[2] = sz[sl][2]; zt[3] = sz[sl][3];
    }
}

// ---------------------------------------------------------------------------
// K5+K6 merged: per-token top-64 (wave 0) + recon from bf16 Wb (reads
// out_i/out_v straight from LDS). No enc writes here -> no race on Wb.
// Also emits the tok lists to d_ws for zero_scatter.
// ---------------------------------------------------------------------------
__global__ __launch_bounds__(256) void tok_recon(
    const int* __restrict__ win_idx, const float* __restrict__ ztab,
    const unsigned short* __restrict__ zh128,
    const unsigned short* __restrict__ Wb, const float* __restrict__ bdec,
    float* __restrict__ recon,
    int* __restrict__ tok_idx, float* __restrict__ tok_val)
{
    const int bid = blockIdx.x;            // token = b*256 + t
    const int t = bid & 255, b = bid >> 8;
    const int tid = threadIdx.x;
    const int lane = tid & 63, wv = tid >> 6;

    __shared__ int l1[64], l2[64];
    __shared__ int out_i[64];
    __shared__ float out_v[64];
    __shared__ int eq_i[130];
    __shared__ float eq_v[130];
    __shared__ int cnt, eqc, s_npos, s_n1;

    const int wlo = (t >= 2) ? ((t - 2) >> 1) : 0;
    int whi = t >> 1; if (whi > NWIN - 1) whi = NWIN - 1;
    const bool valid2 = (whi != wlo);

    int idx1 = -1, idx2 = -1;
    float z1 = 0.f, z2 = 0.f;
    if (wv == 0) {
        const int g1 = (b * NWIN + wlo) * 64 + lane;
        idx1 = win_idx[g1];
        z1 = ztab[(size_t)g1 * 4 + (t - 2 * wlo)];
        if (valid2) {
            const int g2 = (b * NWIN + whi) * 64 + lane;
            idx2 = win_idx[g2];
            z2 = ztab[(size_t)g2 * 4 + (t - 2 * whi)];
        }
        l1[lane] = idx1; l2[lane] = idx2;
        if (lane == 0) { cnt = 0; eqc = 0; s_n1 = 0; }
    }
    __syncthreads();

    if (wv == 0) {
        bool in2 = false, dup2 = false;
        for (int j = 0; j < 64; j++) {
            in2  |= (idx1 == l2[j]);
            dup2 |= (idx2 == l1[j]);
        }
        const float fv1 = in2 ? 2.0f * z1 : z1;
        const bool c2 = valid2 && !dup2;
        const float fv2 = c2 ? z2 : 0.0f;
        const bool pos1 = (fv1 > 0.0f);
        const bool pos2 = c2 && (fv2 > 0.0f);
        const unsigned long long m1 = __ballot(pos1);
        const unsigned long long m2 = __ballot(pos2);
        const int npos = __popcll(m1) + __popcll(m2);
        if (lane == 0) s_npos = npos;

        if (npos > 64) {
            unsigned lo = 0u, hi = 0x43000000u;
            while (lo < hi) {
                const unsigned mid = (lo + hi) >> 1;
                const float fm = __uint_as_float(mid);
                const int c = __popcll(__ballot(pos1 && fv1 > fm)) +
                              __popcll(__ballot(pos2 && fv2 > fm));
                if (c >= 64) lo = mid + 1; else hi = mid;
            }
            const float tau = __uint_as_float(lo);
            const int n1 = __popcll(__ballot(pos1 && fv1 > tau)) +
                           __popcll(__ballot(pos2 && fv2 > tau));
            if (lane == 0) s_n1 = n1;
            if (pos1 && fv1 > tau) { const int s = atomicAdd(&cnt, 1); out_i[s] = idx1; out_v[s] = z1; }
            if (pos2 && fv2 > tau) { const int s = atomicAdd(&cnt, 1); out_i[s] = idx2; out_v[s] = z2; }
            if (pos1 && fv1 == tau) { const int s = atomicAdd(&eqc, 1); if (s < 130) { eq_i[s] = idx1; eq_v[s] = z1; } }
            if (pos2 && fv2 == tau) { const int s = atomicAdd(&eqc, 1); if (s < 130) { eq_i[s] = idx2; eq_v[s] = z2; } }
        } else {
            if (pos1) { const int s = atomicAdd(&cnt, 1); out_i[s] = idx1; out_v[s] = z1; }
            if (pos2) { const int s = atomicAdd(&cnt, 1); out_i[s] = idx2; out_v[s] = z2; }
            const int need = 64 - npos;
            const int d1 = lane, d2 = lane + 64;
            bool ip1 = false, ip2 = false;
            for (int j = 0; j < 64; j++) {
                const int o1 = l1[j]; const bool p1 = (m1 >> j) & 1ull;
                const int o2 = l2[j]; const bool p2 = (m2 >> j) & 1ull;
                ip1 |= (p1 && o1 == d1) || (p2 && o2 == d1);
                ip2 |= (p1 && o1 == d2) || (p2 && o2 == d2);
            }
            const unsigned long long av1 = __ballot(!ip1);
            const unsigned long long av2 = __ballot(!ip2);
            const unsigned long long below = (1ull << lane) - 1ull;
            const int r1 = __popcll(av1 & below);
            const int na1 = __popcll(av1);
            const int r2 = na1 + __popcll(av2 & below);
            if (!ip1 && r1 < need) {
                bool incand = false;
                for (int j = 0; j < 64; j++) incand |= (l1[j] == d1) || (l2[j] == d1);
                const float zv = incand ? 0.0f
                    : (float)((const _Float16*)zh128)[(size_t)bid * 128 + d1];
                const int s = atomicAdd(&cnt, 1); out_i[s] = d1; out_v[s] = zv;
            }
            if (!ip2 && r2 < need) {
                bool incand = false;
                for (int j = 0; j < 64; j++) incand |= (l1[j] == d2) || (l2[j] == d2);
                const float zv = incand ? 0.0f
                    : (float)((const _Float16*)zh128)[(size_t)bid * 128 + d2];
                const int s = atomicAdd(&cnt, 1); out_i[s] = d2; out_v[s] = zv;
            }
        }
    }
    __syncthreads();
    if (tid == 0 && s_npos > 64) {               // tie-fill (lowest index first)
        const int n1 = s_n1, need = 64 - n1;
        int ec = (eqc < 130) ? eqc : 130;
        for (int a = 0; a < need; a++) {
            int best = a;
            for (int q = a + 1; q < ec; q++)
                if (eq_i[q] < eq_i[best]) best = q;
            const int ti = eq_i[a]; eq_i[a] = eq_i[best]; eq_i[best] = ti;
            const float tv = eq_v[a]; eq_v[a] = eq_v[best]; eq_v[best] = tv;
            out_i[n1 + a] = eq_i[a]; out_v[n1 + a] = eq_v[a];
        }
    }
    __syncthreads();

    // tok lists for zero_scatter
    if (tid < 64) {
        tok_idx[bid * 64 + tid] = out_i[tid];
        tok_val[bid * 64 + tid] = out_v[tid];
    }

    // recon from bf16 Wb rows, indices/values from LDS
    if (tid < 192) {
        const int c = tid * 4;                // 4 consecutive cols, 8B in Wb
        const float4 bd = *(const float4*)(bdec + c);
        float a0 = bd.x, a1 = bd.y, a2 = bd.z, a3 = bd.w;
#pragma unroll 8
        for (int j = 0; j < 64; j++) {
            const uint2 pv = *(const uint2*)(Wb + (size_t)out_i[j] * CDIM + c);
            const float vj = out_v[j];
            a0 = fmaf(vj, bf2f((unsigned short)(pv.x & 0xffffu)), a0);
            a1 = fmaf(vj, bf2f((unsigned short)(pv.x >> 16)), a1);
            a2 = fmaf(vj, bf2f((unsigned short)(pv.y & 0xffffu)), a2);
            a3 = fmaf(vj, bf2f((unsigned short)(pv.y >> 16)), a3);
        }
        float4 o; o.x = a0; o.y = a1; o.z = a2; o.w = a3;
        *(float4*)(recon + (size_t)bid * CDIM + c) = o;
    }
}

// ---------------------------------------------------------------------------
// K7: fused zero + scatter (no write amplification)
// ---------------------------------------------------------------------------
__global__ __launch_bounds__(256) void zero_scatter(
    const int* __restrict__ tok_idx, const float* __restrict__ tok_val,
    float* __restrict__ enc)
{
    const int bid = blockIdx.x;
    const int tid = threadIdx.x;
    float* row = enc + (size_t)bid * DICT;
    const float4 z4 = {0.f, 0.f, 0.f, 0.f};
#pragma unroll
    for (int k = 0; k < 16; k++)                 // 256 thr * 16 * 4 = 16384
        *(float4*)(row + (k * 256 + tid) * 4) = z4;
    __syncthreads();
    if (tid < 64)
        row[tok_idx[bid * 64 + tid]] = tok_val[bid * 64 + tid];
}

// ---------------------------------------------------------------------------
extern "C" void kernel_launch(void* const* d_in, const int* in_sizes, int n_in,
                              void* d_out, int out_size, void* d_ws, size_t ws_size,
                              hipStream_t stream)
{
    const float* x    = (const float*)d_in[0];
    const float* Wenc = (const float*)d_in[1];
    const float* benc = (const float*)d_in[2];
    const float* bdec = (const float*)d_in[4];
    (void)in_sizes; (void)n_in; (void)out_size; (void)ws_size;

    float* recon = (float*)d_out;
    float* enc   = recon + (size_t)NTOK * CDIM;          // 134,217,728 bytes

    // scratch layout inside the enc output region (all consumed pre-zero)
    char* base = (char*)enc;
    unsigned short* wsum  = (unsigned short*)(base);                 // 33,292,288
    unsigned short* Wb    = (unsigned short*)(base + 33292288);      // 25,165,824
    unsigned short* xb    = (unsigned short*)(base + 58458112);      //  3,145,728
    unsigned short* zedge = (unsigned short*)(base + 61603840);      //  1,048,576
    unsigned short* zh128 = (unsigned short*)(base + 62652416);      //    524,288
    int*   wini           = (int*)(base + 63176704);                 //    260,096
    float* ztab           = (float*)(base + 63436800);               //  1,040,384

    // tok lists must survive the zeroing -> d_ws (1.0 MB)
    int*   tok_i = (int*)d_ws;
    float* tok_v = (float*)((char*)d_ws + (size_t)NTOK * 64 * 4);

    prep<<<dim3(6912), 256, 0, stream>>>(Wenc, x, bdec, Wb, xb);
    gemm_bf16<<<dim3(NTOK / 128, DICT / 128), 256, 0, stream>>>(xb, Wb, benc,
                                                                wsum, zedge, zh128);
    win_select<<<dim3(BATCH * NWIN), 256, 0, stream>>>(wsum, zedge, x, Wenc,
                                                       benc, bdec, wini, ztab);
    tok_recon<<<dim3(NTOK), 256, 0, stream>>>(wini, ztab, zh128, Wb, bdec,
                                              recon, tok_i, tok_v);
    zero_scatter<<<dim3(NTOK), 256, 0, stream>>>(tok_i, tok_v, enc);
}